// Round 4
// baseline (188.368 us; speedup 1.0000x reference)
//
#include <hip/hip_runtime.h>

#define PI_F 3.14159265358979323846f

__device__ __forceinline__ float rcpf_(float x){ return __builtin_amdgcn_rcpf(x); }
__device__ __forceinline__ float sqrtf_(float x){ return __builtin_amdgcn_sqrtf(x); }

// m in [0,1] by construction (unit vectors, z>=0); clamp dropped.
__device__ __forceinline__ float schlick5(float u){
    float m = 1.0f - u;
    float m2 = m * m;
    return m2 * m2 * m;
}

// Derived-uniform layout in d_ws (22 floats):
// 0:rough 1:sub 2:ax2 3:ay2 4:inv_ax2 5:inv_ay2 6:k_ds 7:a2m1 8:k_dr 9:cc_q
// 10..12:dcol 13..15:scol 16..18:cs0 19..21:(1-cs0)
__device__ __forceinline__ void compute_uniforms(
    const float* bc, float mtl, float sub, float spec, float rough,
    float sp_tint, float aniso, float sh, float sh_tint, float cc, float ccg,
    float* u)
{
    const float cd0 = __powf(bc[0], 2.2f);
    const float cd1 = __powf(bc[1], 2.2f);
    const float cd2 = __powf(bc[2], 2.2f);
    const float lum = 0.3f*cd0 + 0.6f*cd1 + 0.1f*cd2;
    const float il  = rcpf_(fmaxf(lum, 1e-20f));
    const float ct0 = (lum > 0.f) ? cd0*il : 0.f;
    const float ct1 = (lum > 0.f) ? cd1*il : 0.f;
    const float ct2 = (lum > 0.f) ? cd2*il : 0.f;

    const float s008 = spec * 0.08f;
    const float b0 = s008 * (1.f + sp_tint*(ct0 - 1.f));
    const float b1 = s008 * (1.f + sp_tint*(ct1 - 1.f));
    const float b2 = s008 * (1.f + sp_tint*(ct2 - 1.f));
    const float cs0_0 = b0 + mtl*(cd0 - b0);
    const float cs0_1 = b1 + mtl*(cd1 - b1);
    const float cs0_2 = b2 + mtl*(cd2 - b2);

    const float om = 1.f - mtl;
    const float invpi = 1.f / PI_F;

    const float aspect = sqrtf_(1.f - aniso*0.9f);
    const float r2 = rough * rough;
    const float ax = fmaxf(0.001f, r2 * rcpf_(aspect));
    const float ay = fmaxf(0.001f, r2 * aspect);

    const float a_cc = 0.1f + (0.001f - 0.1f)*ccg;
    const float a2 = a_cc * a_cc;
    float a2m1, k_dr;
    if (a_cc >= 1.0f) { a2m1 = 0.f; k_dr = invpi; }
    else              { a2m1 = a2 - 1.f; k_dr = (a2 - 1.f) * rcpf_(PI_F * __logf(a2)); }

    u[0] = rough;
    u[1] = sub;
    u[2] = ax*ax;
    u[3] = ay*ay;
    u[4] = rcpf_(ax*ax);
    u[5] = rcpf_(ay*ay);
    u[6] = rcpf_(PI_F * ax * ay);
    u[7] = a2m1;
    u[8] = k_dr;
    u[9] = 0.25f * cc;
    u[10] = cd0 * om * invpi;
    u[11] = cd1 * om * invpi;
    u[12] = cd2 * om * invpi;
    u[13] = sh * (1.f + sh_tint*(ct0 - 1.f)) * om;
    u[14] = sh * (1.f + sh_tint*(ct1 - 1.f)) * om;
    u[15] = sh * (1.f + sh_tint*(ct2 - 1.f)) * om;
    u[16] = cs0_0;
    u[17] = cs0_1;
    u[18] = cs0_2;
    u[19] = 1.f - cs0_0;
    u[20] = 1.f - cs0_1;
    u[21] = 1.f - cs0_2;
}

__global__ void setup_kernel(
    const float* __restrict__ bc, const float* __restrict__ metallic,
    const float* __restrict__ subsurface, const float* __restrict__ specular,
    const float* __restrict__ roughness, const float* __restrict__ specular_tint,
    const float* __restrict__ anisotropic, const float* __restrict__ sheen,
    const float* __restrict__ sheen_tint, const float* __restrict__ clear_coat,
    const float* __restrict__ clear_coat_gloss, float* __restrict__ ws)
{
    if (threadIdx.x == 0) {
        float u[22];
        compute_uniforms(bc, metallic[0], subsurface[0], specular[0], roughness[0],
                         specular_tint[0], anisotropic[0], sheen[0], sheen_tint[0],
                         clear_coat[0], clear_coat_gloss[0], u);
        #pragma unroll
        for (int i = 0; i < 22; ++i) ws[i] = u[i];
    }
}

// 4 points per thread: 6x float4 in (96B), 3x float4 out (48B).
// __launch_bounds__(256, 4): 4 waves/SIMD min -> 128 VGPR budget, no spills.
__global__ __launch_bounds__(256, 4) void brdf_kernel(
    const float* __restrict__ in,          // (N,2,3)
    const float* __restrict__ uws,         // 22 derived uniforms
    float* __restrict__ out,               // (N,3)
    int npts)
{
    float U[22];
    #pragma unroll
    for (int i = 0; i < 22; ++i) U[i] = uws[i];

    const float rough   = U[0],  sub     = U[1];
    const float ax2     = U[2],  ay2     = U[3];
    const float inv_ax2 = U[4],  inv_ay2 = U[5];
    const float k_ds    = U[6],  a2m1    = U[7];
    const float k_dr    = U[8],  cc_q    = U[9];
    const float two_rough = 2.f * rough;

    int t = blockIdx.x * blockDim.x + threadIdx.x;
    if ((long)t * 4 >= npts) return;

    const float4* in4 = reinterpret_cast<const float4*>(in) + (size_t)t * 6;
    float4 q0 = in4[0], q1 = in4[1], q2 = in4[2], q3 = in4[3], q4 = in4[4], q5 = in4[5];

    auto shade = [&](float l0, float l1, float l2, float v0, float v1, float v2,
                     float& o0, float& o1, float& o2) {
        // un-normalized half vector; for unit l,v: cos_hl = |hv|/2, chl^2 = n2/4
        const float hvx = l0 + v0, hvy = l1 + v1, hvz = l2 + v2;
        const float n2 = hvx*hvx + hvy*hvy + hvz*hvz;
        const float chl = 0.5f * sqrtf_(n2);
        const float chl2 = 0.25f * n2;

        const bool valid = (l2 >= 0.f) && (v2 >= 0.f);
        const float cnl = valid ? l2 : 0.5f;
        const float cnv = valid ? v2 : 0.5f;

        const float fl = schlick5(cnl);
        const float fv = schlick5(cnv);
        const float FH = schlick5(chl);

        const float fd90m1  = two_rough * chl2 - 0.5f;
        const float fd  = (1.f + fd90m1*fl) * (1.f + fd90m1*fv);
        const float fss90m1 = rough * chl2 - 1.f;
        const float fss = (1.f + fss90m1*fl) * (1.f + fss90m1*fv);
        const float ss = 1.25f * (fss * (rcpf_(cnl + cnv) - 0.5f) + 0.5f);
        const float dw = fd + sub * (ss - fd);

        // anisotropic GGX specular over un-normalized hv; Gs*Ds in ONE rcp
        const float dtermu = hvx*hvx*inv_ax2 + hvy*hvy*inv_ay2 + hvz*hvz;
        const float denL = cnl + sqrtf_(l0*l0*ax2 + l1*l1*ay2 + cnl*cnl);
        const float denV = cnv + sqrtf_(v0*v0*ax2 + v1*v1*ay2 + cnv*cnv);
        const float GsDs = k_ds * (n2 * n2) * rcpf_(dtermu*dtermu * denL * denV);

        // clearcoat, whole term in ONE rcp
        const float tden = n2 + a2m1 * (hvz*hvz);
        const float grL = cnl + sqrtf_(0.0625f + 0.9375f*cnl*cnl);
        const float grV = cnv + sqrtf_(0.0625f + 0.9375f*cnv*cnv);
        const float Fr = 0.04f + 0.96f * FH;
        const float clear = cc_q * Fr * k_dr * n2 * rcpf_(tden * grL * grV);

        float r0 = dw*U[10] + FH*U[13] + GsDs*(U[16] + FH*U[19]) + clear;
        float r1 = dw*U[11] + FH*U[14] + GsDs*(U[17] + FH*U[20]) + clear;
        float r2 = dw*U[12] + FH*U[15] + GsDs*(U[18] + FH*U[21]) + clear;

        o0 = valid ? r0 : 0.f;
        o1 = valid ? r1 : 0.f;
        o2 = valid ? r2 : 0.f;
    };

    float a0,a1,a2v, b0,b1,b2v, c0,c1,c2v, d0,d1,d2v;
    shade(q0.x,q0.y,q0.z, q0.w,q1.x,q1.y, a0,a1,a2v);
    shade(q1.z,q1.w,q2.x, q2.y,q2.z,q2.w, b0,b1,b2v);
    shade(q3.x,q3.y,q3.z, q3.w,q4.x,q4.y, c0,c1,c2v);
    shade(q4.z,q4.w,q5.x, q5.y,q5.z,q5.w, d0,d1,d2v);

    float4* out4 = reinterpret_cast<float4*>(out) + (size_t)t * 3;
    out4[0] = make_float4(a0, a1, a2v, b0);
    out4[1] = make_float4(b1, b2v, c0, c1);
    out4[2] = make_float4(c2v, d0, d1, d2v);
}

extern "C" void kernel_launch(void* const* d_in, const int* in_sizes, int n_in,
                              void* d_out, int out_size, void* d_ws, size_t ws_size,
                              hipStream_t stream) {
    const float* in = (const float*)d_in[0];
    const int npts = in_sizes[0] / 6;           // (N,2,3) -> N
    const int nthreads = npts / 4;              // 4 points per thread
    const int block = 256;
    const int grid = (nthreads + block - 1) / block;

    float* ws = (float*)d_ws;
    setup_kernel<<<1, 64, 0, stream>>>(
        (const float*)d_in[1], (const float*)d_in[2], (const float*)d_in[3],
        (const float*)d_in[4], (const float*)d_in[5], (const float*)d_in[6],
        (const float*)d_in[7], (const float*)d_in[8], (const float*)d_in[9],
        (const float*)d_in[10], (const float*)d_in[11], ws);

    brdf_kernel<<<grid, block, 0, stream>>>(in, ws, (float*)d_out, npts);
}

// Round 6
// 181.742 us; speedup vs baseline: 1.0365x; 1.0365x over previous
//
#include <hip/hip_runtime.h>

#define PI_F 3.14159265358979323846f
#define THREADS 256
#define PTS_PER_BLOCK 512   // 2 points per thread

__device__ __forceinline__ float rcpf_(float x){ return __builtin_amdgcn_rcpf(x); }
__device__ __forceinline__ float sqrtf_(float x){ return __builtin_amdgcn_sqrtf(x); }

__device__ __forceinline__ float schlick5(float u){
    float m = 1.0f - u;
    float m2 = m * m;
    return m2 * m2 * m;
}

// Derived-uniform layout in d_ws (22 floats):
// 0:rough 1:sub 2:ax2 3:ay2 4:inv_ax2 5:inv_ay2 6:k_ds 7:a2m1 8:k_dr 9:cc_q
// 10..12:dcol 13..15:scol 16..18:cs0 19..21:(1-cs0)
__device__ __forceinline__ void compute_uniforms(
    const float* bc, float mtl, float sub, float spec, float rough,
    float sp_tint, float aniso, float sh, float sh_tint, float cc, float ccg,
    float* u)
{
    const float cd0 = __powf(bc[0], 2.2f);
    const float cd1 = __powf(bc[1], 2.2f);
    const float cd2 = __powf(bc[2], 2.2f);
    const float lum = 0.3f*cd0 + 0.6f*cd1 + 0.1f*cd2;
    const float il  = rcpf_(fmaxf(lum, 1e-20f));
    const float ct0 = (lum > 0.f) ? cd0*il : 0.f;
    const float ct1 = (lum > 0.f) ? cd1*il : 0.f;
    const float ct2 = (lum > 0.f) ? cd2*il : 0.f;

    const float s008 = spec * 0.08f;
    const float b0 = s008 * (1.f + sp_tint*(ct0 - 1.f));
    const float b1 = s008 * (1.f + sp_tint*(ct1 - 1.f));
    const float b2 = s008 * (1.f + sp_tint*(ct2 - 1.f));
    const float cs0_0 = b0 + mtl*(cd0 - b0);
    const float cs0_1 = b1 + mtl*(cd1 - b1);
    const float cs0_2 = b2 + mtl*(cd2 - b2);

    const float om = 1.f - mtl;
    const float invpi = 1.f / PI_F;

    const float aspect = sqrtf_(1.f - aniso*0.9f);
    const float r2 = rough * rough;
    const float ax = fmaxf(0.001f, r2 * rcpf_(aspect));
    const float ay = fmaxf(0.001f, r2 * aspect);

    const float a_cc = 0.1f + (0.001f - 0.1f)*ccg;
    const float a2 = a_cc * a_cc;
    float a2m1, k_dr;
    if (a_cc >= 1.0f) { a2m1 = 0.f; k_dr = invpi; }
    else              { a2m1 = a2 - 1.f; k_dr = (a2 - 1.f) * rcpf_(PI_F * __logf(a2)); }

    u[0] = rough;
    u[1] = sub;
    u[2] = ax*ax;
    u[3] = ay*ay;
    u[4] = rcpf_(ax*ax);
    u[5] = rcpf_(ay*ay);
    u[6] = rcpf_(PI_F * ax * ay);
    u[7] = a2m1;
    u[8] = k_dr;
    u[9] = 0.25f * cc;
    u[10] = cd0 * om * invpi;
    u[11] = cd1 * om * invpi;
    u[12] = cd2 * om * invpi;
    u[13] = sh * (1.f + sh_tint*(ct0 - 1.f)) * om;
    u[14] = sh * (1.f + sh_tint*(ct1 - 1.f)) * om;
    u[15] = sh * (1.f + sh_tint*(ct2 - 1.f)) * om;
    u[16] = cs0_0;
    u[17] = cs0_1;
    u[18] = cs0_2;
    u[19] = 1.f - cs0_0;
    u[20] = 1.f - cs0_1;
    u[21] = 1.f - cs0_2;
}

__global__ void setup_kernel(
    const float* __restrict__ bc, const float* __restrict__ metallic,
    const float* __restrict__ subsurface, const float* __restrict__ specular,
    const float* __restrict__ roughness, const float* __restrict__ specular_tint,
    const float* __restrict__ anisotropic, const float* __restrict__ sheen,
    const float* __restrict__ sheen_tint, const float* __restrict__ clear_coat,
    const float* __restrict__ clear_coat_gloss, float* __restrict__ ws)
{
    if (threadIdx.x == 0) {
        float u[22];
        compute_uniforms(bc, metallic[0], subsurface[0], specular[0], roughness[0],
                         specular_tint[0], anisotropic[0], sheen[0], sheen_tint[0],
                         clear_coat[0], clear_coat_gloss[0], u);
        #pragma unroll
        for (int i = 0; i < 22; ++i) ws[i] = u[i];
    }
}

// Coalesced via LDS staging: block of 256 threads handles 512 points.
// Phase 1: 3x dwordx4 coalesced global->LDS (12KB).
// Phase 2: 2 points/thread, AoS reads from LDS (<=4-way bank alias, ~free).
// Phase 3: outputs via LDS (6KB), 3x dwordx2 coalesced stores.
__global__ __launch_bounds__(THREADS, 4) void brdf_kernel(
    const float* __restrict__ in,          // (N,2,3)
    const float* __restrict__ uws,         // 22 derived uniforms
    float* __restrict__ out,               // (N,3)
    int npts)
{
    __shared__ float4 s_in4[PTS_PER_BLOCK * 6 / 4];   // 12 KB, 16B aligned
    __shared__ float2 s_out2[PTS_PER_BLOCK * 3 / 2];  //  6 KB
    float* s_in = reinterpret_cast<float*>(s_in4);
    float* s_out = reinterpret_cast<float*>(s_out2);

    float U[22];
    #pragma unroll
    for (int i = 0; i < 22; ++i) U[i] = uws[i];
    const float rough   = U[0],  sub     = U[1];
    const float ax2     = U[2],  ay2     = U[3];
    const float inv_ax2 = U[4],  inv_ay2 = U[5];
    const float k_ds    = U[6],  a2m1    = U[7];
    const float k_dr    = U[8],  cc_q    = U[9];
    const float two_rough = 2.f * rough;

    const int j = threadIdx.x;
    const size_t blk = blockIdx.x;

    // ---- phase 1: coalesced load to LDS ----
    const size_t total_f4 = (size_t)npts * 6 / 4;
    const float4* gin = reinterpret_cast<const float4*>(in);
    const size_t f4_base = blk * (PTS_PER_BLOCK * 6 / 4);
    #pragma unroll
    for (int k = 0; k < 3; ++k) {
        size_t idx = f4_base + j + k * THREADS;
        if (idx < total_f4) s_in4[j + k * THREADS] = gin[idx];
    }
    __syncthreads();

    // ---- phase 2: shade 2 points ----
    #pragma unroll
    for (int k = 0; k < 2; ++k) {
        const int p = j + k * THREADS;
        const float l0 = s_in[6*p+0], l1 = s_in[6*p+1], l2 = s_in[6*p+2];
        const float v0 = s_in[6*p+3], v1 = s_in[6*p+4], v2 = s_in[6*p+5];

        // un-normalized half vector; for unit l,v: cos_hl = |hv|/2, chl^2 = n2/4
        const float hvx = l0 + v0, hvy = l1 + v1, hvz = l2 + v2;
        const float n2 = hvx*hvx + hvy*hvy + hvz*hvz;
        const float chl = 0.5f * sqrtf_(n2);
        const float chl2 = 0.25f * n2;

        const bool valid = (l2 >= 0.f) && (v2 >= 0.f);
        const float cnl = valid ? l2 : 0.5f;
        const float cnv = valid ? v2 : 0.5f;

        const float fl = schlick5(cnl);
        const float fv = schlick5(cnv);
        const float FH = schlick5(chl);

        const float fd90m1  = two_rough * chl2 - 0.5f;
        const float fd  = (1.f + fd90m1*fl) * (1.f + fd90m1*fv);
        const float fss90m1 = rough * chl2 - 1.f;
        const float fss = (1.f + fss90m1*fl) * (1.f + fss90m1*fv);
        const float ss = 1.25f * (fss * (rcpf_(cnl + cnv) - 0.5f) + 0.5f);
        const float dw = fd + sub * (ss - fd);

        // anisotropic GGX specular over un-normalized hv; Gs*Ds in ONE rcp
        const float dtermu = hvx*hvx*inv_ax2 + hvy*hvy*inv_ay2 + hvz*hvz;
        const float denL = cnl + sqrtf_(l0*l0*ax2 + l1*l1*ay2 + cnl*cnl);
        const float denV = cnv + sqrtf_(v0*v0*ax2 + v1*v1*ay2 + cnv*cnv);
        const float GsDs = k_ds * (n2 * n2) * rcpf_(dtermu*dtermu * denL * denV);

        // clearcoat, whole term in ONE rcp
        const float tden = n2 + a2m1 * (hvz*hvz);
        const float grL = cnl + sqrtf_(0.0625f + 0.9375f*cnl*cnl);
        const float grV = cnv + sqrtf_(0.0625f + 0.9375f*cnv*cnv);
        const float Fr = 0.04f + 0.96f * FH;
        const float clear = cc_q * Fr * k_dr * n2 * rcpf_(tden * grL * grV);

        float r0 = dw*U[10] + FH*U[13] + GsDs*(U[16] + FH*U[19]) + clear;
        float r1 = dw*U[11] + FH*U[14] + GsDs*(U[17] + FH*U[20]) + clear;
        float r2 = dw*U[12] + FH*U[15] + GsDs*(U[18] + FH*U[21]) + clear;

        s_out[3*p+0] = valid ? r0 : 0.f;
        s_out[3*p+1] = valid ? r1 : 0.f;
        s_out[3*p+2] = valid ? r2 : 0.f;
    }
    __syncthreads();

    // ---- phase 3: coalesced store from LDS ----
    const size_t total_f2 = (size_t)npts * 3 / 2;
    float2* gout = reinterpret_cast<float2*>(out);
    const size_t f2_base = blk * (PTS_PER_BLOCK * 3 / 2);
    #pragma unroll
    for (int k = 0; k < 3; ++k) {
        size_t idx = f2_base + j + k * THREADS;
        if (idx < total_f2) gout[idx] = s_out2[j + k * THREADS];
    }
}

extern "C" void kernel_launch(void* const* d_in, const int* in_sizes, int n_in,
                              void* d_out, int out_size, void* d_ws, size_t ws_size,
                              hipStream_t stream) {
    const float* in = (const float*)d_in[0];
    const int npts = in_sizes[0] / 6;                 // (N,2,3) -> N
    const int grid = (npts + PTS_PER_BLOCK - 1) / PTS_PER_BLOCK;

    float* ws = (float*)d_ws;
    setup_kernel<<<1, 64, 0, stream>>>(
        (const float*)d_in[1], (const float*)d_in[2], (const float*)d_in[3],
        (const float*)d_in[4], (const float*)d_in[5], (const float*)d_in[6],
        (const float*)d_in[7], (const float*)d_in[8], (const float*)d_in[9],
        (const float*)d_in[10], (const float*)d_in[11], ws);

    brdf_kernel<<<grid, THREADS, 0, stream>>>(in, ws, (float*)d_out, npts);
}